// Round 12
// baseline (477.341 us; speedup 1.0000x reference)
//
#include <hip/hip_runtime.h>
#include <hip/hip_bf16.h>
#include <math.h>

// ---------------------------------------------------------------------------
// Transformer block, MI355X/gfx950. bf16 MFMA compute, fp32 accumulate.
// x:[4,2048,1024] f32. M = 8192 tokens, DIM=1024, HEADS=16, DHEAD=64, MLP=4096.
// attn: R5 in-register-P + R10 bh-major XCD-local grid (FETCH 139->26 MB).
// GEMMs: gemm_bt 128^2 (8-phase retired: 3 ports ~30% MfmaUtil vs 34-36%).
// R9: prep fusion. R11: V-transpose fused into qkv epilogue (EPI=3).
// R12: attn K/V double-buffer + one-tile-ahead prefetch. R2's pipelining
//   failed via L3/HBM refetch from de-synced sharers; R10 removed that
//   mechanism (sharers same-XCD, 4 MB working set = L2-resident, FETCH
//   already ~min). Stage(t+1) issued at top of iter t; compute covers the
//   L2 latency; vmcnt(0)+barrier only at iter end. WAR/RAW audited.
// ---------------------------------------------------------------------------

typedef __bf16 bf16;
typedef __bf16 bf16x8 __attribute__((ext_vector_type(8)));
typedef __bf16 bf16x4 __attribute__((ext_vector_type(4)));
typedef __bf16 bf16x2 __attribute__((ext_vector_type(2)));
typedef float  f32x4  __attribute__((ext_vector_type(4)));
typedef unsigned int u32;
typedef u32 u32x4 __attribute__((ext_vector_type(4)));

#define MFMA_16x16x32(a, b, c) __builtin_amdgcn_mfma_f32_16x16x32_bf16((a), (b), (c), 0, 0, 0)

// cross-lane quad redistribution primitives (gfx950)
#define SWAP32(x, y) asm("v_permlane32_swap_b32 %0, %1" : "+v"(x), "+v"(y))
#define SWAP16(x, y) asm("v_permlane16_swap_b32 %0, %1" : "+v"(x), "+v"(y))

__device__ __forceinline__ void gl_lds16(const void* g, void* l) {
    __builtin_amdgcn_global_load_lds(
        (const __attribute__((address_space(1))) u32*)g,
        (__attribute__((address_space(3))) u32*)l, 16, 0, 0);
}

__device__ __forceinline__ u32 pack_bf16x2(float a, float b) {
    bf16x2 t; t[0] = (bf16)a; t[1] = (bf16)b;   // compiler emits v_cvt_pk_bf16_f32
    return __builtin_bit_cast(u32, t);
}

// fast exact-enough GELU: tanh form, e = exp2(2u*log2e), g = x*e/(e+1)
__device__ __forceinline__ float fast_gelu(float x) {
    const float u = x * (0.7978845608028654f + 0.03567740814183f * x * x);
    const float e = __builtin_amdgcn_exp2f(u * 2.8853900817779268f);
    return x * e * __builtin_amdgcn_rcpf(e + 1.0f);
}

// ---------------------------------------------------------------------------
// prep_kernel: 4 weight transposes (f32 [R][C] -> bf16 [C][R]) + ln1, fused.
// ---------------------------------------------------------------------------
__device__ __forceinline__ void transpose_body(
    const float* __restrict__ in, bf16* __restrict__ out, int R, int C,
    int bx, int by, float (*tile)[33])
{
    const int cb = bx * 32, rb = by * 32;
    const int c = threadIdx.x & 31, r0 = threadIdx.x >> 5;
#pragma unroll
    for (int i = 0; i < 4; ++i) {
        int r = r0 + i * 8;
        tile[r][c] = in[(size_t)(rb + r) * C + cb + c];
    }
    __syncthreads();
#pragma unroll
    for (int i = 0; i < 4; ++i) {
        int rr = r0 + i * 8;
        out[(size_t)(cb + rr) * R + rb + c] = (bf16)tile[c][rr];
    }
}

__device__ __forceinline__ void ln_body(
    const float* __restrict__ x, const float* __restrict__ g,
    const float* __restrict__ b, bf16* __restrict__ out, int bid)
{
    const int lane = threadIdx.x & 63;
    const int wv   = threadIdx.x >> 6;
    const size_t token = (size_t)bid * 4 + wv;
    const float* xr = x + token * 1024;
    float4 v[4];
    float s = 0.f, ss = 0.f;
#pragma unroll
    for (int c = 0; c < 4; ++c) {
        v[c] = *(const float4*)(xr + c * 256 + lane * 4);
        s  += v[c].x + v[c].y + v[c].z + v[c].w;
        ss += v[c].x * v[c].x + v[c].y * v[c].y + v[c].z * v[c].z + v[c].w * v[c].w;
    }
#pragma unroll
    for (int off = 32; off > 0; off >>= 1) {
        s  += __shfl_xor(s, off);
        ss += __shfl_xor(ss, off);
    }
    const float mu  = s * (1.0f / 1024.0f);
    const float var = ss * (1.0f / 1024.0f) - mu * mu;
    const float rs  = rsqrtf(var + 1e-5f);
    bf16* orow = out + token * 1024;
#pragma unroll
    for (int c = 0; c < 4; ++c) {
        float4 gg = *(const float4*)(g + c * 256 + lane * 4);
        float4 bb = *(const float4*)(b + c * 256 + lane * 4);
        bf16x4 o;
        o[0] = (bf16)((v[c].x - mu) * rs * gg.x + bb.x);
        o[1] = (bf16)((v[c].y - mu) * rs * gg.y + bb.y);
        o[2] = (bf16)((v[c].z - mu) * rs * gg.z + bb.z);
        o[3] = (bf16)((v[c].w - mu) * rs * gg.w + bb.w);
        *(bf16x4*)(orow + c * 256 + lane * 4) = o;
    }
}

__global__ __launch_bounds__(256) void prep_kernel(
    const float* __restrict__ w_qkv, const float* __restrict__ w_out,
    const float* __restrict__ w1,    const float* __restrict__ w2,
    bf16* __restrict__ wT_qkv, bf16* __restrict__ wT_out,
    bf16* __restrict__ wT_1,   bf16* __restrict__ wT_2,
    const float* __restrict__ x, const float* __restrict__ g,
    const float* __restrict__ b, bf16* __restrict__ h)
{
    __shared__ float tile[32][33];
    const int id = blockIdx.x;
    if (id < 3072) {
        transpose_body(w_qkv, wT_qkv, 1024, 3072, id % 96, id / 96, tile);
    } else if (id < 4096) {
        const int j = id - 3072;
        transpose_body(w_out, wT_out, 1024, 1024, j & 31, j >> 5, tile);
    } else if (id < 8192) {
        const int j = id - 4096;
        transpose_body(w1, wT_1, 1024, 4096, j & 127, j >> 7, tile);
    } else if (id < 12288) {
        const int j = id - 8192;
        transpose_body(w2, wT_2, 4096, 1024, j & 31, j >> 5, tile);
    } else {
        ln_body(x, g, b, h, id - 12288);
    }
}

// ---------------------------------------------------------------------------
// ln_kernel (standalone, for ln2 which depends on proj output)
// ---------------------------------------------------------------------------
__global__ __launch_bounds__(256) void ln_kernel(
    const float* __restrict__ x, const float* __restrict__ g,
    const float* __restrict__ b, bf16* __restrict__ out)
{
    ln_body(x, g, b, out, blockIdx.x);
}

// ---------------------------------------------------------------------------
// GEMM: A[M,K] bf16 x Bt[N,K] bf16 -> out [M,N]. 128x128 tile, BK=64,
// two-barrier K-loop. LINE-COALESCED staging; chunk XOR folded into the
// GLOBAL address so LDS stays linear for gl_lds16.
// EPI: 0 = bf16; 1 = +bias +resid(f32) -> f32; 2 = +bias, fast GELU -> bf16
//      3 = qkv fused-V-transpose: N0<2048 -> bf16 rows to outp;
//          N0>=2048 -> transposed scalar stores into VT (passed via resid).
// ---------------------------------------------------------------------------
template <int EPI>
__global__ __launch_bounds__(256, 4) void gemm_bt(
    const bf16* __restrict__ A, const bf16* __restrict__ Bt,
    const float* __restrict__ bias, const float* __restrict__ resid,
    void* __restrict__ outp, int M, int N, int K)
{
    __shared__ __align__(16) bf16 sA[128 * 64];   // 16 KB
    __shared__ __align__(16) bf16 sB[128 * 64];   // 16 KB

    const int tid  = threadIdx.x;
    const int lane = tid & 63;
    const int wv   = tid >> 6;
    const int quad = lane >> 4;
    const int l16  = lane & 15;

    // XCD slab swizzle (HW heuristic: XCD = linear block id % 8)
    const int id  = blockIdx.x;
    const int xcd = id & 7, j = id >> 3;
    const int M0 = (xcd * 8 + (j & 7)) * 128;   // Mb = 64 fixed (M == 8192)
    const int N0 = (j >> 3) * 128;

    const int wm = (wv >> 1) * 64;
    const int wn = (wv & 1) * 64;

    f32x4 acc[4][4] = {};

    const bf16* paG[4];
    const bf16* pbG[4];
#pragma unroll
    for (int c = 0; c < 4; ++c) {
        const int f = c * 256 + tid;
        const int row = f >> 3;
        const int gch = (f & 7) ^ (row & 7);
        paG[c] = A  + (size_t)(M0 + row) * K + gch * 8;
        pbG[c] = Bt + (size_t)(N0 + row) * K + gch * 8;
    }

    const int sw = l16 & 7;

    for (int k0 = 0; k0 < K; k0 += 64) {
        __syncthreads();
#pragma unroll
        for (int c = 0; c < 4; ++c) {
            const int f8 = (c * 256 + tid) * 8;
            gl_lds16(paG[c] + k0, sA + f8);
            gl_lds16(pbG[c] + k0, sB + f8);
        }
        __syncthreads();

#pragma unroll
        for (int s = 0; s < 2; ++s) {
            const int chp = (s * 4 + quad) ^ sw;   // swizzled chunk position
            bf16x8 af[4], bfr[4];
#pragma unroll
            for (int t = 0; t < 4; ++t)
                af[t] = *(const bf16x8*)(sA + ((wm + t * 16 + l16) << 6) + chp * 8);
#pragma unroll
            for (int t = 0; t < 4; ++t)
                bfr[t] = *(const bf16x8*)(sB + ((wn + t * 16 + l16) << 6) + chp * 8);
#pragma unroll
            for (int tm = 0; tm < 4; ++tm)
#pragma unroll
                for (int tn = 0; tn < 4; ++tn)
                    acc[tm][tn] = MFMA_16x16x32(bfr[tn], af[tm], acc[tm][tn]);
        }
    }

    // swapped C layout: lane l16 = output row, regs r = 4 consecutive cols
#pragma unroll
    for (int tm = 0; tm < 4; ++tm) {
        const int row = M0 + wm + tm * 16 + l16;
#pragma unroll
        for (int tn = 0; tn < 4; ++tn) {
            const int col = N0 + wn + tn * 16 + quad * 4;
            const size_t idx = (size_t)row * N + col;
            const f32x4 v = acc[tm][tn];
            if (EPI == 0) {
                bf16x4 o;
#pragma unroll
                for (int r = 0; r < 4; ++r) o[r] = (bf16)v[r];
                *(bf16x4*)((bf16*)outp + idx) = o;
            } else if (EPI == 1) {
                const f32x4 b4 = *(const f32x4*)(bias + col);
                const f32x4 r4 = *(const f32x4*)(resid + idx);
                *(f32x4*)((float*)outp + idx) = v + b4 + r4;
            } else if (EPI == 2) {
                const f32x4 b4 = *(const f32x4*)(bias + col);
                bf16x4 o;
#pragma unroll
                for (int r = 0; r < 4; ++r) o[r] = (bf16)fast_gelu(v[r] + b4[r]);
                *(bf16x4*)((bf16*)outp + idx) = o;
            } else {
                // EPI == 3: qkv with fused V-transpose
                if (N0 < 2048) {
                    bf16x4 o;
#pragma unroll
                    for (int r = 0; r < 4; ++r) o[r] = (bf16)v[r];
                    *(bf16x4*)((bf16*)outp + idx) = o;
                } else {
                    bf16* VTp = (bf16*)resid;   // VT base (reinterpreted)
                    const int bq  = row >> 11;
                    const int tok = row & 2047;
                    const int hd0 = bq * 1024 + (col - 2048);
#pragma unroll
                    for (int r = 0; r < 4; ++r)
                        VTp[(size_t)(hd0 + r) * 2048 + tok] = (bf16)v[r];
                }
            }
        }
    }
}

// ---------------------------------------------------------------------------
// Flash attention (R5 structure + R10 XCD-local grid + R12 double-buffer).
// Per iter: issue stage(t+1 -> buf^1); compute t from buf (QK+softmax+PV
// covers the L2 load latency); vmcnt(0)+barrier at END (t+1 landed, all
// waves past reads of buf before iter t+1's stage overwrites it at t+2).
// LDS: sK 2x8K + sV 2x8K = 32 KB -> 4 blocks/CU.
// ---------------------------------------------------------------------------
__global__ __launch_bounds__(256, 4) void attn_kernel(
    const bf16* __restrict__ qkv, const bf16* __restrict__ VT,
    bf16* __restrict__ attn_out)
{
    __shared__ __align__(16) bf16 sK[2][4096];
    __shared__ __align__(16) bf16 sV[2][4096];

    const int bh = blockIdx.x, b = bh >> 4, h = bh & 15;   // bh on x (R10)
    const int tid = threadIdx.x, lane = tid & 63, wv = tid >> 6;
    const int quad = lane >> 4, l16 = lane & 15;
    const size_t tok0 = (size_t)b * 2048;
    const int q0 = blockIdx.y * 128 + wv * 32;             // q-tile on y

    bf16x8 qf[2][2];
#pragma unroll
    for (int mi = 0; mi < 2; ++mi)
#pragma unroll
        for (int c = 0; c < 2; ++c) {
            bf16x8 t = *(const bf16x8*)(qkv + (tok0 + q0 + mi * 16 + l16) * 3072 + h * 64 + c * 32 + quad * 8);
#pragma unroll
            for (int j = 0; j < 8; ++j) t[j] = (bf16)((float)t[j] * 0.18033688011112042f);
            qf[mi][c] = t;
        }

    f32x4 o[2][4] = {};
    float lsum[2] = {0.f, 0.f};

    const int fA = tid, fB = tid + 256;
    const int cKA = fA >> 8, keyA = (fA >> 2) & 63, qcA = fA & 3;
    const int cKB = fB >> 8, keyB = (fB >> 2) & 63, qcB = fB & 3;
    const int dVA = fA >> 3, ccA = fA & 7;
    const int dVB = fB >> 3, ccB = fB & 7;
    const bf16* Kb = qkv + 1024 + h * 64;
    const bf16* Vb = VT + (size_t)bh * 64 * 2048;

    // hoisted per-thread staging bases (add kb-dependent offset per tile)
    const bf16* KgA = Kb + (tok0 + keyA) * 3072 + cKA * 32 + ((qcA ^ (keyA & 3)) * 8);
    const bf16* KgB = Kb + (tok0 + keyB) * 3072 + cKB * 32 + ((qcB ^ (keyB & 3)) * 8);
    const bf16* VgA = Vb + (size_t)dVA * 2048 + ((ccA ^ (dVA & 7)) * 8);
    const bf16* VgB = Vb + (size_t)dVB * 2048 + ((ccB ^ (dVB & 7)) * 8);

    auto STAGE = [&](int kt, int buf) {
        const int kb = kt * 64;
        gl_lds16(KgA + (size_t)kb * 3072, sK[buf] + fA * 8);
        gl_lds16(KgB + (size_t)kb * 3072, sK[buf] + fB * 8);
        gl_lds16(VgA + kb, sV[buf] + fA * 8);
        gl_lds16(VgB + kb, sV[buf] + fB * 8);
    };

    // prologue: tile 0 -> buf 0
    STAGE(0, 0);
    asm volatile("s_waitcnt vmcnt(0)" ::: "memory");
    __builtin_amdgcn_s_barrier();

    for (int kt = 0; kt < 32; ++kt) {
        const int cur = kt & 1;
        // prefetch next tile into the other buffer (issued before compute;
        // lands before the end-of-iter vmcnt(0))
        if (kt + 1 < 32) STAGE(kt + 1, cur ^ 1);

        const bf16* sKc = sK[cur];
        const bf16* sVc = sV[cur];

        // ---- swapped QK^T + exp + pack: w[mi][ct][c2] per lane ----
        u32 w[2][4][2];
        __builtin_amdgcn_s_setprio(1);
#pragma unroll
        for (int ct = 0; ct < 4; ++ct) {
            const int key = ct * 16 + l16;
            const int ch = quad ^ (l16 & 3);
            bf16x8 k0 = *(const bf16x8*)(sKc + (key * 4 + ch) * 8);
            bf16x8 k1 = *(const bf16x8*)(sKc + (256 + key * 4 + ch) * 8);
#pragma unroll
            for (int mi = 0; mi < 2; ++mi) {
                f32x4 z = {};
                z = MFMA_16x16x32(k0, qf[mi][0], z);
                z = MFMA_16x16x32(k1, qf[mi][1], z);
                float p0 = __builtin_amdgcn_exp2f(z[0]);
                float p1 = __builtin_amdgcn_exp2f(z[1]);
                float p2 = __builtin_amdgcn_exp2f(z[2]);
                float p3 = __builtin_amdgcn_exp2f(z[3]);
                lsum[mi] += (p0 + p1) + (p2 + p3);
                w[mi][ct][0] = pack_bf16x2(p0, p1);
                w[mi][ct][1] = pack_bf16x2(p2, p3);
            }
        }
        __builtin_amdgcn_s_setprio(0);

        // ---- quad redistribution -> PV A-operands (in-register) ----
        bf16x8 pa[2][2];
#pragma unroll
        for (int mi = 0; mi < 2; ++mi) {
            u32 pw0[4], pw1[4];
#pragma unroll
            for (int c2 = 0; c2 < 2; ++c2) {
                u32 x = w[mi][0][c2], y = w[mi][1][c2];
                SWAP32(x, y); SWAP16(x, y);
                pw0[c2] = x; pw0[2 + c2] = y;
                u32 x2 = w[mi][2][c2], y2 = w[mi][3][c2];
                SWAP32(x2, y2); SWAP16(x2, y2);
                pw1[c2] = x2; pw1[2 + c2] = y2;
            }
            u32x4 t0 = {pw0[0], pw0[1], pw0[2], pw0[3]};
            u32x4 t1 = {pw1[0], pw1[1], pw1[2], pw1[3]};
            pa[mi][0] = __builtin_bit_cast(bf16x8, t0);
            pa[mi][1] = __builtin_bit_cast(bf16x8, t1);
        }

        // ---- PV ----
        __builtin_amdgcn_s_setprio(1);
#pragma unroll
        for (int dt = 0; dt < 4; ++dt) {
            const int d = dt * 16 + l16;
            bf16x8 v0 = *(const bf16x8*)(sVc + (d * 8 + (quad ^ (l16 & 7))) * 8);
            bf16x8 v1 = *(const bf16x8*)(sVc + (d * 8 + ((quad + 4) ^ (l16 & 7))) * 8);
#pragma unroll
            for (int mi = 0; mi < 2; ++mi) {
                o[mi][dt] = MFMA_16x16x32(pa[mi][0], v0, o[mi][dt]);
                o[mi][dt] = MFMA_16x16x32(pa[mi][1], v1, o[mi][dt]);
            }
        }
        __builtin_amdgcn_s_setprio(0);

        // next tile landed; all waves past their reads of the current buf
        asm volatile("s_waitcnt vmcnt(0)" ::: "memory");
        __builtin_amdgcn_s_barrier();
    }

    // epilogue: lsum lives at q=l16; reduce over quads, broadcast to (quad,r)
#pragma unroll
    for (int mi = 0; mi < 2; ++mi) {
        float t = lsum[mi];
        t += __shfl_xor(t, 16);
        t += __shfl_xor(t, 32);
        float rl[4];
#pragma unroll
        for (int r = 0; r < 4; ++r) rl[r] = 1.0f / __shfl(t, quad * 4 + r);
#pragma unroll
        for (int dt = 0; dt < 4; ++dt)
#pragma unroll
            for (int r = 0; r < 4; ++r) {
                const size_t tok = tok0 + q0 + mi * 16 + quad * 4 + r;
                attn_out[tok * 1024 + h * 64 + dt * 16 + l16] = (bf16)(o[mi][dt][r] * rl[r]);
            }
    }
}

// ---------------------------------------------------------------------------
extern "C" void kernel_launch(void* const* d_in, const int* in_sizes, int n_in,
                              void* d_out, int out_size, void* d_ws, size_t ws_size,
                              hipStream_t stream)
{
    const float* x     = (const float*)d_in[0];
    const float* ln1_g = (const float*)d_in[1];
    const float* ln1_b = (const float*)d_in[2];
    const float* w_qkv = (const float*)d_in[3];
    const float* w_out = (const float*)d_in[4];
    const float* b_out = (const float*)d_in[5];
    const float* ln2_g = (const float*)d_in[6];
    const float* ln2_b = (const float*)d_in[7];
    const float* w1    = (const float*)d_in[8];
    const float* b1    = (const float*)d_in[9];
    const float* w2    = (const float*)d_in[10];
    const float* b2    = (const float*)d_in[11];
    float* out = (float*)d_out;

    char* ws = (char*)d_ws;
    bf16*  h      = (bf16*)(ws);                    // 16 MB
    bf16*  big    = (bf16*)(ws + 16777216);         // 64 MB (qkv, then mlp1)
    bf16*  attn_o = (bf16*)(ws + 83886080);         // 16 MB
    float* x_mid  = (float*)(ws + 100663296);       // 32 MB
    bf16*  VT     = (bf16*)(ws + 100663296);        // 16 MB (dead before x_mid)
    bf16*  wT_qkv = (bf16*)(ws + 134217728);
    bf16*  wT_out = (bf16*)(ws + 140509184);
    bf16*  wT_1   = (bf16*)(ws + 142606336);
    bf16*  wT_2   = (bf16*)(ws + 150994944);

    // fused: 4 weight transposes + ln1 (5 launches -> 1)
    prep_kernel<<<14336, 256, 0, stream>>>(w_qkv, w_out, w1, w2,
                                           wT_qkv, wT_out, wT_1, wT_2,
                                           x, ln1_g, ln1_b, h);

    // qkv with fused V-transpose (EPI=3): V-part written directly into VT
    gemm_bt<3><<<64 * 24, 256, 0, stream>>>(h, wT_qkv, nullptr,
                                            (const float*)VT, big,
                                            8192, 3072, 1024);

    // R10: bh-major grid -> XCD-local K/V sharing
    attn_kernel<<<dim3(64, 16), 256, 0, stream>>>(big, VT, attn_o);

    gemm_bt<1><<<64 * 8, 256, 0, stream>>>(attn_o, wT_out, b_out, x, x_mid, 8192, 1024, 1024);

    ln_kernel<<<2048, 256, 0, stream>>>(x_mid, ln2_g, ln2_b, h);

    gemm_bt<2><<<64 * 32, 256, 0, stream>>>(h, wT_1, b1, nullptr, big, 8192, 4096, 1024);

    gemm_bt<1><<<64 * 8, 256, 0, stream>>>(big, wT_2, b2, x_mid, out, 8192, 1024, 4096);
}

// Round 13
// 437.549 us; speedup vs baseline: 1.0909x; 1.0909x over previous
//
#include <hip/hip_runtime.h>
#include <hip/hip_bf16.h>
#include <math.h>

// ---------------------------------------------------------------------------
// Transformer block, MI355X/gfx950. bf16 MFMA compute, fp32 accumulate.
// x:[4,2048,1024] f32. M = 8192 tokens, DIM=1024, HEADS=16, DHEAD=64, MLP=4096.
// FINAL (R11 config, best measured: 447.9 us).
// attn: R5 in-register P (swapped QK^T + permlane32/16_swap; sP eliminated)
//   + R10 bh-major grid (XCD-local K/V: FETCH 139->25 MB). 81-83 us,
//   latency-chain bound (survived +-2x occupancy/tile, 2 pipelining fails).
// GEMMs: gemm_bt 128^2 two-barrier (34-36% MfmaUtil ceiling; 8-phase ports
//   measured worse on this problem's K=1024/4096 shapes, 3 variants).
// prep_kernel: 4 weight transposes + ln1 fused (5 launches -> 1).
// qkv EPI=3: V-transpose fused into GEMM epilogue (kernel + 32 MB removed).
// ---------------------------------------------------------------------------

typedef __bf16 bf16;
typedef __bf16 bf16x8 __attribute__((ext_vector_type(8)));
typedef __bf16 bf16x4 __attribute__((ext_vector_type(4)));
typedef __bf16 bf16x2 __attribute__((ext_vector_type(2)));
typedef float  f32x4  __attribute__((ext_vector_type(4)));
typedef unsigned int u32;
typedef u32 u32x4 __attribute__((ext_vector_type(4)));

#define MFMA_16x16x32(a, b, c) __builtin_amdgcn_mfma_f32_16x16x32_bf16((a), (b), (c), 0, 0, 0)

// cross-lane quad redistribution primitives (gfx950)
#define SWAP32(x, y) asm("v_permlane32_swap_b32 %0, %1" : "+v"(x), "+v"(y))
#define SWAP16(x, y) asm("v_permlane16_swap_b32 %0, %1" : "+v"(x), "+v"(y))

__device__ __forceinline__ void gl_lds16(const void* g, void* l) {
    __builtin_amdgcn_global_load_lds(
        (const __attribute__((address_space(1))) u32*)g,
        (__attribute__((address_space(3))) u32*)l, 16, 0, 0);
}

__device__ __forceinline__ u32 pack_bf16x2(float a, float b) {
    bf16x2 t; t[0] = (bf16)a; t[1] = (bf16)b;   // compiler emits v_cvt_pk_bf16_f32
    return __builtin_bit_cast(u32, t);
}

// fast exact-enough GELU: tanh form, e = exp2(2u*log2e), g = x*e/(e+1)
__device__ __forceinline__ float fast_gelu(float x) {
    const float u = x * (0.7978845608028654f + 0.03567740814183f * x * x);
    const float e = __builtin_amdgcn_exp2f(u * 2.8853900817779268f);
    return x * e * __builtin_amdgcn_rcpf(e + 1.0f);
}

// ---------------------------------------------------------------------------
// prep_kernel: 4 weight transposes (f32 [R][C] -> bf16 [C][R]) + ln1, fused.
//   [0,3072) w_qkv | [3072,4096) w_out | [4096,8192) w1 | [8192,12288) w2 |
//   [12288,14336) ln1
// ---------------------------------------------------------------------------
__device__ __forceinline__ void transpose_body(
    const float* __restrict__ in, bf16* __restrict__ out, int R, int C,
    int bx, int by, float (*tile)[33])
{
    const int cb = bx * 32, rb = by * 32;
    const int c = threadIdx.x & 31, r0 = threadIdx.x >> 5;
#pragma unroll
    for (int i = 0; i < 4; ++i) {
        int r = r0 + i * 8;
        tile[r][c] = in[(size_t)(rb + r) * C + cb + c];
    }
    __syncthreads();
#pragma unroll
    for (int i = 0; i < 4; ++i) {
        int rr = r0 + i * 8;
        out[(size_t)(cb + rr) * R + rb + c] = (bf16)tile[c][rr];
    }
}

__device__ __forceinline__ void ln_body(
    const float* __restrict__ x, const float* __restrict__ g,
    const float* __restrict__ b, bf16* __restrict__ out, int bid)
{
    const int lane = threadIdx.x & 63;
    const int wv   = threadIdx.x >> 6;
    const size_t token = (size_t)bid * 4 + wv;
    const float* xr = x + token * 1024;
    float4 v[4];
    float s = 0.f, ss = 0.f;
#pragma unroll
    for (int c = 0; c < 4; ++c) {
        v[c] = *(const float4*)(xr + c * 256 + lane * 4);
        s  += v[c].x + v[c].y + v[c].z + v[c].w;
        ss += v[c].x * v[c].x + v[c].y * v[c].y + v[c].z * v[c].z + v[c].w * v[c].w;
    }
#pragma unroll
    for (int off = 32; off > 0; off >>= 1) {
        s  += __shfl_xor(s, off);
        ss += __shfl_xor(ss, off);
    }
    const float mu  = s * (1.0f / 1024.0f);
    const float var = ss * (1.0f / 1024.0f) - mu * mu;
    const float rs  = rsqrtf(var + 1e-5f);
    bf16* orow = out + token * 1024;
#pragma unroll
    for (int c = 0; c < 4; ++c) {
        float4 gg = *(const float4*)(g + c * 256 + lane * 4);
        float4 bb = *(const float4*)(b + c * 256 + lane * 4);
        bf16x4 o;
        o[0] = (bf16)((v[c].x - mu) * rs * gg.x + bb.x);
        o[1] = (bf16)((v[c].y - mu) * rs * gg.y + bb.y);
        o[2] = (bf16)((v[c].z - mu) * rs * gg.z + bb.z);
        o[3] = (bf16)((v[c].w - mu) * rs * gg.w + bb.w);
        *(bf16x4*)(orow + c * 256 + lane * 4) = o;
    }
}

__global__ __launch_bounds__(256) void prep_kernel(
    const float* __restrict__ w_qkv, const float* __restrict__ w_out,
    const float* __restrict__ w1,    const float* __restrict__ w2,
    bf16* __restrict__ wT_qkv, bf16* __restrict__ wT_out,
    bf16* __restrict__ wT_1,   bf16* __restrict__ wT_2,
    const float* __restrict__ x, const float* __restrict__ g,
    const float* __restrict__ b, bf16* __restrict__ h)
{
    __shared__ float tile[32][33];
    const int id = blockIdx.x;
    if (id < 3072) {
        transpose_body(w_qkv, wT_qkv, 1024, 3072, id % 96, id / 96, tile);
    } else if (id < 4096) {
        const int j = id - 3072;
        transpose_body(w_out, wT_out, 1024, 1024, j & 31, j >> 5, tile);
    } else if (id < 8192) {
        const int j = id - 4096;
        transpose_body(w1, wT_1, 1024, 4096, j & 127, j >> 7, tile);
    } else if (id < 12288) {
        const int j = id - 8192;
        transpose_body(w2, wT_2, 4096, 1024, j & 31, j >> 5, tile);
    } else {
        ln_body(x, g, b, h, id - 12288);
    }
}

// ---------------------------------------------------------------------------
// ln_kernel (standalone, for ln2 which depends on proj output)
// ---------------------------------------------------------------------------
__global__ __launch_bounds__(256) void ln_kernel(
    const float* __restrict__ x, const float* __restrict__ g,
    const float* __restrict__ b, bf16* __restrict__ out)
{
    ln_body(x, g, b, out, blockIdx.x);
}

// ---------------------------------------------------------------------------
// GEMM: A[M,K] bf16 x Bt[N,K] bf16 -> out [M,N]. 128x128 tile, BK=64,
// two-barrier K-loop. LINE-COALESCED staging; chunk XOR folded into the
// GLOBAL address so LDS stays linear for gl_lds16.
// EPI: 0 = bf16; 1 = +bias +resid(f32) -> f32; 2 = +bias, fast GELU -> bf16
//      3 = qkv fused-V-transpose: N0<2048 -> bf16 rows to outp;
//          N0>=2048 -> transposed scalar stores into VT (passed via resid).
// ---------------------------------------------------------------------------
template <int EPI>
__global__ __launch_bounds__(256, 4) void gemm_bt(
    const bf16* __restrict__ A, const bf16* __restrict__ Bt,
    const float* __restrict__ bias, const float* __restrict__ resid,
    void* __restrict__ outp, int M, int N, int K)
{
    __shared__ __align__(16) bf16 sA[128 * 64];   // 16 KB
    __shared__ __align__(16) bf16 sB[128 * 64];   // 16 KB

    const int tid  = threadIdx.x;
    const int lane = tid & 63;
    const int wv   = tid >> 6;
    const int quad = lane >> 4;
    const int l16  = lane & 15;

    // XCD slab swizzle (HW heuristic: XCD = linear block id % 8)
    const int id  = blockIdx.x;
    const int xcd = id & 7, j = id >> 3;
    const int M0 = (xcd * 8 + (j & 7)) * 128;   // Mb = 64 fixed (M == 8192)
    const int N0 = (j >> 3) * 128;

    const int wm = (wv >> 1) * 64;
    const int wn = (wv & 1) * 64;

    f32x4 acc[4][4] = {};

    const bf16* paG[4];
    const bf16* pbG[4];
#pragma unroll
    for (int c = 0; c < 4; ++c) {
        const int f = c * 256 + tid;
        const int row = f >> 3;
        const int gch = (f & 7) ^ (row & 7);
        paG[c] = A  + (size_t)(M0 + row) * K + gch * 8;
        pbG[c] = Bt + (size_t)(N0 + row) * K + gch * 8;
    }

    const int sw = l16 & 7;

    for (int k0 = 0; k0 < K; k0 += 64) {
        __syncthreads();
#pragma unroll
        for (int c = 0; c < 4; ++c) {
            const int f8 = (c * 256 + tid) * 8;
            gl_lds16(paG[c] + k0, sA + f8);
            gl_lds16(pbG[c] + k0, sB + f8);
        }
        __syncthreads();

#pragma unroll
        for (int s = 0; s < 2; ++s) {
            const int chp = (s * 4 + quad) ^ sw;   // swizzled chunk position
            bf16x8 af[4], bfr[4];
#pragma unroll
            for (int t = 0; t < 4; ++t)
                af[t] = *(const bf16x8*)(sA + ((wm + t * 16 + l16) << 6) + chp * 8);
#pragma unroll
            for (int t = 0; t < 4; ++t)
                bfr[t] = *(const bf16x8*)(sB + ((wn + t * 16 + l16) << 6) + chp * 8);
#pragma unroll
            for (int tm = 0; tm < 4; ++tm)
#pragma unroll
                for (int tn = 0; tn < 4; ++tn)
                    acc[tm][tn] = MFMA_16x16x32(bfr[tn], af[tm], acc[tm][tn]);
        }
    }

    // swapped C layout: lane l16 = output row, regs r = 4 consecutive cols
#pragma unroll
    for (int tm = 0; tm < 4; ++tm) {
        const int row = M0 + wm + tm * 16 + l16;
#pragma unroll
        for (int tn = 0; tn < 4; ++tn) {
            const int col = N0 + wn + tn * 16 + quad * 4;
            const size_t idx = (size_t)row * N + col;
            const f32x4 v = acc[tm][tn];
            if (EPI == 0) {
                bf16x4 o;
#pragma unroll
                for (int r = 0; r < 4; ++r) o[r] = (bf16)v[r];
                *(bf16x4*)((bf16*)outp + idx) = o;
            } else if (EPI == 1) {
                const f32x4 b4 = *(const f32x4*)(bias + col);
                const f32x4 r4 = *(const f32x4*)(resid + idx);
                *(f32x4*)((float*)outp + idx) = v + b4 + r4;
            } else if (EPI == 2) {
                const f32x4 b4 = *(const f32x4*)(bias + col);
                bf16x4 o;
#pragma unroll
                for (int r = 0; r < 4; ++r) o[r] = (bf16)fast_gelu(v[r] + b4[r]);
                *(bf16x4*)((bf16*)outp + idx) = o;
            } else {
                // EPI == 3: qkv with fused V-transpose
                if (N0 < 2048) {
                    bf16x4 o;
#pragma unroll
                    for (int r = 0; r < 4; ++r) o[r] = (bf16)v[r];
                    *(bf16x4*)((bf16*)outp + idx) = o;
                } else {
                    // VT[(b*1024 + (col-2048))*2048 + (row&2047)]
                    // 16-row runs are 16-aligned -> never cross the 2048
                    // token boundary: b, tok uniform per store.
                    bf16* VTp = (bf16*)resid;   // VT base (reinterpreted)
                    const int bq  = row >> 11;
                    const int tok = row & 2047;
                    const int hd0 = bq * 1024 + (col - 2048);
#pragma unroll
                    for (int r = 0; r < 4; ++r)
                        VTp[(size_t)(hd0 + r) * 2048 + tok] = (bf16)v[r];
                }
            }
        }
    }
}

// ---------------------------------------------------------------------------
// Flash attention (R5 structure): no-max softmax, swapped QK^T, in-register
// P via permlane32/16_swap. R10 grid (64 bh, 16 q-tiles): id%8 == bh%8 ->
// all 16 K/V sharers of a bh on ONE XCD (L2-local drains; FETCH 139->25 MB).
// LDS: sK 8K + sV 8K. Stage -> full drain -> compute (drain-synced blocks;
// R2/R12 established pipelining regresses in both cache regimes).
// ---------------------------------------------------------------------------
__global__ __launch_bounds__(256, 4) void attn_kernel(
    const bf16* __restrict__ qkv, const bf16* __restrict__ VT,
    bf16* __restrict__ attn_out)
{
    __shared__ __align__(16) bf16 sK[4096];
    __shared__ __align__(16) bf16 sV[4096];

    const int bh = blockIdx.x, b = bh >> 4, h = bh & 15;   // bh on x (R10)
    const int tid = threadIdx.x, lane = tid & 63, wv = tid >> 6;
    const int quad = lane >> 4, l16 = lane & 15;
    const size_t tok0 = (size_t)b * 2048;
    const int q0 = blockIdx.y * 128 + wv * 32;             // q-tile on y

    bf16x8 qf[2][2];
#pragma unroll
    for (int mi = 0; mi < 2; ++mi)
#pragma unroll
        for (int c = 0; c < 2; ++c) {
            bf16x8 t = *(const bf16x8*)(qkv + (tok0 + q0 + mi * 16 + l16) * 3072 + h * 64 + c * 32 + quad * 8);
#pragma unroll
            for (int j = 0; j < 8; ++j) t[j] = (bf16)((float)t[j] * 0.18033688011112042f);
            qf[mi][c] = t;
        }

    f32x4 o[2][4] = {};
    float lsum[2] = {0.f, 0.f};

    const int fA = tid, fB = tid + 256;
    const int cKA = fA >> 8, keyA = (fA >> 2) & 63, qcA = fA & 3;
    const int cKB = fB >> 8, keyB = (fB >> 2) & 63, qcB = fB & 3;
    const int dVA = fA >> 3, ccA = fA & 7;
    const int dVB = fB >> 3, ccB = fB & 7;
    const bf16* Kb = qkv + 1024 + h * 64;
    const bf16* Vb = VT + (size_t)bh * 64 * 2048;

    for (int kt = 0; kt < 32; ++kt) {
        const int kb = kt * 64;
        __syncthreads();
        gl_lds16(Kb + (tok0 + kb + keyA) * 3072 + cKA * 32 + ((qcA ^ (keyA & 3)) * 8), sK + fA * 8);
        gl_lds16(Kb + (tok0 + kb + keyB) * 3072 + cKB * 32 + ((qcB ^ (keyB & 3)) * 8), sK + fB * 8);
        gl_lds16(Vb + (size_t)dVA * 2048 + kb + ((ccA ^ (dVA & 7)) * 8), sV + fA * 8);
        gl_lds16(Vb + (size_t)dVB * 2048 + kb + ((ccB ^ (dVB & 7)) * 8), sV + fB * 8);
        __syncthreads();

        // ---- swapped QK^T + exp + pack: w[mi][ct][c2] per lane ----
        u32 w[2][4][2];
        __builtin_amdgcn_s_setprio(1);
#pragma unroll
        for (int ct = 0; ct < 4; ++ct) {
            const int key = ct * 16 + l16;
            const int ch = quad ^ (l16 & 3);
            bf16x8 k0 = *(const bf16x8*)(sK + (key * 4 + ch) * 8);
            bf16x8 k1 = *(const bf16x8*)(sK + (256 + key * 4 + ch) * 8);
#pragma unroll
            for (int mi = 0; mi < 2; ++mi) {
                f32x4 z = {};
                z = MFMA_16x16x32(k0, qf[mi][0], z);
                z = MFMA_16x16x32(k1, qf[mi][1], z);
                float p0 = __builtin_amdgcn_exp2f(z[0]);
                float p1 = __builtin_amdgcn_exp2f(z[1]);
                float p2 = __builtin_amdgcn_exp2f(z[2]);
                float p3 = __builtin_amdgcn_exp2f(z[3]);
                lsum[mi] += (p0 + p1) + (p2 + p3);
                w[mi][ct][0] = pack_bf16x2(p0, p1);
                w[mi][ct][1] = pack_bf16x2(p2, p3);
            }
        }
        __builtin_amdgcn_s_setprio(0);

        // ---- quad redistribution -> PV A-operands (in-register) ----
        bf16x8 pa[2][2];
#pragma unroll
        for (int mi = 0; mi < 2; ++mi) {
            u32 pw0[4], pw1[4];
#pragma unroll
            for (int c2 = 0; c2 < 2; ++c2) {
                u32 x = w[mi][0][c2], y = w[mi][1][c2];
                SWAP32(x, y); SWAP16(x, y);
                pw0[c2] = x; pw0[2 + c2] = y;
                u32 x2 = w[mi][2][c2], y2 = w[mi][3][c2];
                SWAP32(x2, y2); SWAP16(x2, y2);
                pw1[c2] = x2; pw1[2 + c2] = y2;
            }
            u32x4 t0 = {pw0[0], pw0[1], pw0[2], pw0[3]};
            u32x4 t1 = {pw1[0], pw1[1], pw1[2], pw1[3]};
            pa[mi][0] = __builtin_bit_cast(bf16x8, t0);
            pa[mi][1] = __builtin_bit_cast(bf16x8, t1);
        }

        // ---- PV ----
        __builtin_amdgcn_s_setprio(1);
#pragma unroll
        for (int dt = 0; dt < 4; ++dt) {
            const int d = dt * 16 + l16;
            bf16x8 v0 = *(const bf16x8*)(sV + (d * 8 + (quad ^ (l16 & 7))) * 8);
            bf16x8 v1 = *(const bf16x8*)(sV + (d * 8 + ((quad + 4) ^ (l16 & 7))) * 8);
#pragma unroll
            for (int mi = 0; mi < 2; ++mi) {
                o[mi][dt] = MFMA_16x16x32(pa[mi][0], v0, o[mi][dt]);
                o[mi][dt] = MFMA_16x16x32(pa[mi][1], v1, o[mi][dt]);
            }
        }
        __builtin_amdgcn_s_setprio(0);
    }

    // epilogue: lsum lives at q=l16; reduce over quads, broadcast to (quad,r)
#pragma unroll
    for (int mi = 0; mi < 2; ++mi) {
        float t = lsum[mi];
        t += __shfl_xor(t, 16);
        t += __shfl_xor(t, 32);
        float rl[4];
#pragma unroll
        for (int r = 0; r < 4; ++r) rl[r] = 1.0f / __shfl(t, quad * 4 + r);
#pragma unroll
        for (int dt = 0; dt < 4; ++dt)
#pragma unroll
            for (int r = 0; r < 4; ++r) {
                const size_t tok = tok0 + q0 + mi * 16 + quad * 4 + r;
                attn_out[tok * 1024 + h * 64 + dt * 16 + l16] = (bf16)(o[mi][dt][r] * rl[r]);
            }
    }
}

// ---------------------------------------------------------------------------
extern "C" void kernel_launch(void* const* d_in, const int* in_sizes, int n_in,
                              void* d_out, int out_size, void* d_ws, size_t ws_size,
                              hipStream_t stream)
{
    const float* x     = (const float*)d_in[0];
    const float* ln1_g = (const float*)d_in[1];
    const float* ln1_b = (const float*)d_in[2];
    const float* w_qkv = (const float*)d_in[3];
    const float* w_out = (const float*)d_in[4];
    const float* b_out = (const float*)d_in[5];
    const float* ln2_g = (const float*)d_in[6];
    const float* ln2_b = (const float*)d_in[7];
    const float* w1    = (const float*)d_in[8];
    const float* b1    = (const float*)d_in[9];
    const float* w2    = (const float*)d_in[10];
    const float* b2    = (const float*)d_in[11];
    float* out = (float*)d_out;

    char* ws = (char*)d_ws;
    bf16*  h      = (bf16*)(ws);                    // 16 MB
    bf16*  big    = (bf16*)(ws + 16777216);         // 64 MB (qkv, then mlp1)
    bf16*  attn_o = (bf16*)(ws + 83886080);         // 16 MB
    float* x_mid  = (float*)(ws + 100663296);       // 32 MB
    bf16*  VT     = (bf16*)(ws + 100663296);        // 16 MB (dead before x_mid)
    bf16*  wT_qkv = (bf16*)(ws + 134217728);
    bf16*  wT_out = (bf16*)(ws + 140509184);
    bf16*  wT_1   = (bf16*)(ws + 142606336);
    bf16*  wT_2   = (bf16*)(ws + 150994944);

    // fused: 4 weight transposes + ln1 (5 launches -> 1)
    prep_kernel<<<14336, 256, 0, stream>>>(w_qkv, w_out, w1, w2,
                                           wT_qkv, wT_out, wT_1, wT_2,
                                           x, ln1_g, ln1_b, h);

    // qkv with fused V-transpose (EPI=3): V-part written directly into VT
    gemm_bt<3><<<64 * 24, 256, 0, stream>>>(h, wT_qkv, nullptr,
                                            (const float*)VT, big,
                                            8192, 3072, 1024);

    // R10: bh-major grid -> XCD-local K/V sharing
    attn_kernel<<<dim3(64, 16), 256, 0, stream>>>(big, VT, attn_o);

    gemm_bt<1><<<64 * 8, 256, 0, stream>>>(attn_o, wT_out, b_out, x, x_mid, 8192, 1024, 1024);

    ln_kernel<<<2048, 256, 0, stream>>>(x_mid, ln2_g, ln2_b, h);

    gemm_bt<2><<<64 * 32, 256, 0, stream>>>(h, wT_1, b1, nullptr, big, 8192, 4096, 1024);

    gemm_bt<1><<<64 * 8, 256, 0, stream>>>(big, wT_2, b2, x_mid, out, 8192, 1024, 4096);
}